// Round 6
// baseline (117.911 us; speedup 1.0000x reference)
//
#include <hip/hip_runtime.h>
#include <hip/hip_fp16.h>

#define NUM_CAMS 6
#define B_DIM    2
#define C_DIM    64
#define H_DIM    232
#define W_DIM    400
#define HW_DIM   (H_DIM * W_DIM)          // 92800
#define TILES_PER_PLANE (HW_DIM / 64)     // 1450 (exact)
#define PLANES   (NUM_CAMS * B_DIM)       // 12

typedef float f4 __attribute__((ext_vector_type(4)));
typedef unsigned int u32;
typedef unsigned char u8;

// ---------------------------------------------------------------------------
// zero the per-pixel reference flags (1.1 MB) — must be rebuilt every call
// ---------------------------------------------------------------------------
__global__ __launch_bounds__(256) void zero_flags_kernel(u32* __restrict__ f, int n32)
{
    const int t = blockIdx.x * 256 + threadIdx.x;
    if (t < n32) f[t] = 0u;
}

// ---------------------------------------------------------------------------
// mark pixel-slots referenced by any masked point (benign u8 store races)
// grid = (ceil(N/256), NUM_CAMS)
// ---------------------------------------------------------------------------
__global__ __launch_bounds__(256) void flag_kernel(
    const int* __restrict__ bidx, const int* __restrict__ gy,
    const int* __restrict__ gx, const int* __restrict__ mask,
    u8* __restrict__ flags, int N)
{
    const int n = blockIdx.x * 256 + threadIdx.x;
    const int k = blockIdx.y;
    if (n >= N) return;
    if (mask[(size_t)k * N + n] > 0) {
        const int plane = k * B_DIM + bidx[n];
        const int pix = gy[(size_t)k * N + n] * W_DIM + gx[(size_t)k * N + n];
        flags[(size_t)plane * HW_DIM + pix] = 1;
    }
}

// ---------------------------------------------------------------------------
// Transpose + downconvert: (k,b,c,h,w) fp32 -> (k,b,h,w,c) fp16, writing only
// pixels whose flag is set (each pixel = one aligned 128B granule).
// img read once -> non-temporal. flags==nullptr -> write everything.
// ---------------------------------------------------------------------------
__global__ __launch_bounds__(256) void transpose_f16_kernel(
    const float* __restrict__ img,   // (12, 64, HW)
    __half*      __restrict__ wsp,   // (12, HW, 64)
    const u8*    __restrict__ flags) // (12, HW) or nullptr
{
    __shared__ float tile[64][65];   // [channel][pixel], +1 pad

    const int t   = blockIdx.x;
    const int kb  = blockIdx.y;
    const int px0 = t * 64;
    const size_t plane_in  = (size_t)kb * C_DIM * HW_DIM;
    const size_t plane_out = (size_t)kb * HW_DIM * C_DIM;
    const int tid = threadIdx.x;

    {
        const int pq = tid & 15;     // which float4 along the 64 pixels
        const int cg = tid >> 4;     // 0..15
#pragma unroll
        for (int r = 0; r < 4; ++r) {
            const int c = r * 16 + cg;
            const f4 v = __builtin_nontemporal_load(
                (const f4*)&img[plane_in + (size_t)c * HW_DIM + px0 + pq * 4]);
            tile[c][pq * 4 + 0] = v.x;
            tile[c][pq * 4 + 1] = v.y;
            tile[c][pq * 4 + 2] = v.z;
            tile[c][pq * 4 + 3] = v.w;
        }
    }
    __syncthreads();
    {
        const int c2 = (tid & 31) * 2;  // channel pair
        const int pg = tid >> 5;        // 0..7
#pragma unroll
        for (int r = 0; r < 8; ++r) {
            const int p = r * 8 + pg;
            const bool wr = (flags == nullptr) || (flags[(size_t)kb * HW_DIM + px0 + p] != 0);
            if (wr) {
                const __half2 h = __floats2half2_rn(tile[c2][p], tile[c2 + 1][p]);
                *(__half2*)&wsp[plane_out + (size_t)(px0 + p) * C_DIM + c2] = h;
            }
        }
    }
}

// ---------------------------------------------------------------------------
// Fuse: 16 lanes per voxel, each lane owns 4 channels. Gather per camera is
// one contiguous 128B (fp16) read from the (L3-resident) sparse copy.
// ---------------------------------------------------------------------------
__global__ __launch_bounds__(256) void fuse_f16_kernel(
    const __half* __restrict__ wsp,  // (12, HW, 64) channel-last fp16
    const float*  __restrict__ vox,  // (N, 64)
    const int*    __restrict__ bidx, // (N,)
    const int*    __restrict__ gy,   // (6, N)
    const int*    __restrict__ gx,   // (6, N)
    const int*    __restrict__ mask, // (6, N)
    float*        __restrict__ out,  // (N, 64)
    int N)
{
    const size_t gt = blockIdx.x * (size_t)blockDim.x + threadIdx.x;
    const int n = (int)(gt >> 4);
    const int q = (int)(gt & 15);
    if (n >= N) return;

    int m[NUM_CAMS], y[NUM_CAMS], x[NUM_CAMS];
#pragma unroll
    for (int k = 0; k < NUM_CAMS; ++k) {
        m[k] = mask[(size_t)k * N + n];
        y[k] = gy[(size_t)k * N + n];
        x[k] = gx[(size_t)k * N + n];
    }
    const int b = bidx[n];

    f4 acc = __builtin_nontemporal_load((const f4*)vox + (size_t)n * 16 + q);

    const __half* base = wsp + (size_t)b * HW_DIM * C_DIM;

    uint2 rv[NUM_CAMS];
#pragma unroll
    for (int k = 0; k < NUM_CAMS; ++k) {
        rv[k] = make_uint2(0u, 0u);           // fp16 zeros
        if (m[k] > 0) {
            const __half* p = base
                + (size_t)k * ((size_t)B_DIM * HW_DIM * C_DIM)
                + ((size_t)y[k] * W_DIM + x[k]) * C_DIM;
            rv[k] = *(const uint2*)(p + q * 4);
        }
    }

#pragma unroll
    for (int k = 0; k < NUM_CAMS; ++k) {
        const __half2 a = *(const __half2*)&rv[k].x;
        const __half2 c = *(const __half2*)&rv[k].y;
        const float2 fa = __half22float2(a);
        const float2 fc = __half22float2(c);
        acc.x += fa.x; acc.y += fa.y; acc.z += fc.x; acc.w += fc.y;
    }

    __builtin_nontemporal_store(acc, (f4*)out + (size_t)n * 16 + q);
}

// ---------------------------------------------------------------------------
// Fallback (round-1 kernel) if the workspace is too small for the fp16 copy.
// ---------------------------------------------------------------------------
__global__ __launch_bounds__(256) void fuse_direct_kernel(
    const float* __restrict__ img, const float* __restrict__ vox,
    const int* __restrict__ bidx, const int* __restrict__ gy,
    const int* __restrict__ gx, const int* __restrict__ mask,
    float* __restrict__ out, int N)
{
    const int wave = (int)((blockIdx.x * (size_t)blockDim.x + threadIdx.x) >> 6);
    const int c    = threadIdx.x & 63;
    if (wave >= N) return;
    const int n = wave;
    int m[NUM_CAMS], y[NUM_CAMS], x[NUM_CAMS];
#pragma unroll
    for (int k = 0; k < NUM_CAMS; ++k) {
        m[k] = mask[(size_t)k * N + n];
        y[k] = gy[(size_t)k * N + n];
        x[k] = gx[(size_t)k * N + n];
    }
    const int b = bidx[n];
    float acc = vox[(size_t)n * C_DIM + c];
    const float* base = img + ((size_t)b * C_DIM + c) * HW_DIM;
    float v[NUM_CAMS];
#pragma unroll
    for (int k = 0; k < NUM_CAMS; ++k) {
        v[k] = 0.0f;
        if (m[k] > 0)
            v[k] = base[(size_t)k * (B_DIM * C_DIM * (size_t)HW_DIM)
                        + (size_t)y[k] * W_DIM + (size_t)x[k]];
    }
    acc += ((v[0] + v[1]) + (v[2] + v[3])) + (v[4] + v[5]);
    out[(size_t)n * C_DIM + c] = acc;
}

extern "C" void kernel_launch(void* const* d_in, const int* in_sizes, int n_in,
                              void* d_out, int out_size, void* d_ws, size_t ws_size,
                              hipStream_t stream) {
    const float* img  = (const float*)d_in[0];
    const float* vox  = (const float*)d_in[1];
    const int*   bidx = (const int*)d_in[2];
    const int*   gy   = (const int*)d_in[3];
    const int*   gx   = (const int*)d_in[4];
    const int*   mask = (const int*)d_in[5];
    float* out = (float*)d_out;

    const int N = in_sizes[2];

    const size_t wsp_bytes   = (size_t)PLANES * HW_DIM * C_DIM * sizeof(__half); // ~142 MB
    const size_t flags_off   = (wsp_bytes + 255) & ~(size_t)255;
    const size_t flags_bytes = (size_t)PLANES * HW_DIM;                          // ~1.1 MB
    const size_t need_flags  = flags_off + flags_bytes;

    dim3 tgrid(TILES_PER_PLANE, PLANES);
    dim3 mgrid((N + 255) / 256, NUM_CAMS);
    const int fuse_blocks = (int)(((size_t)N * 16 + 255) / 256);

    if (ws_size >= need_flags) {
        __half* wsp = (__half*)d_ws;
        u8* flags = (u8*)d_ws + flags_off;

        const int n32 = (int)(flags_bytes / 4);
        zero_flags_kernel<<<(n32 + 255) / 256, 256, 0, stream>>>((u32*)flags, n32);
        flag_kernel<<<mgrid, 256, 0, stream>>>(bidx, gy, gx, mask, flags, N);
        transpose_f16_kernel<<<tgrid, 256, 0, stream>>>(img, wsp, flags);
        fuse_f16_kernel<<<fuse_blocks, 256, 0, stream>>>(wsp, vox, bidx, gy, gx, mask, out, N);
    } else if (ws_size >= wsp_bytes) {
        __half* wsp = (__half*)d_ws;
        transpose_f16_kernel<<<tgrid, 256, 0, stream>>>(img, wsp, nullptr);
        fuse_f16_kernel<<<fuse_blocks, 256, 0, stream>>>(wsp, vox, bidx, gy, gx, mask, out, N);
    } else {
        const int blocks = (N * 64 + 255) / 256;
        fuse_direct_kernel<<<blocks, 256, 0, stream>>>(img, vox, bidx, gy, gx, mask, out, N);
    }
}

// Round 7
// 104.594 us; speedup vs baseline: 1.1273x; 1.1273x over previous
//
#include <hip/hip_runtime.h>
#include <hip/hip_fp16.h>

#define NUM_CAMS 6
#define B_DIM    2
#define C_DIM    64
#define H_DIM    232
#define W_DIM    400
#define HW_DIM   (H_DIM * W_DIM)          // 92800
#define TILES_PER_PLANE (HW_DIM / 64)     // 1450 (exact)
#define PLANES   (NUM_CAMS * B_DIM)       // 12

typedef float f4 __attribute__((ext_vector_type(4)));

// ---------------------------------------------------------------------------
// Transpose + downconvert: (k,b,c,h,w) fp32 -> (k,b,h,w,c) fp16.
// img is read ONCE -> non-temporal loads, so the fp16 copy (written here,
// read by the fuse) keeps Infinity-Cache residency. (Round-5 version; the
// round-6 sparse-write variant regressed: writes are not on the critical
// path, they drain lazily through L3.)
// ---------------------------------------------------------------------------
__global__ __launch_bounds__(256) void transpose_f16_kernel(
    const float* __restrict__ img,   // (12, 64, HW)
    __half*      __restrict__ wsp)   // (12, HW, 64)
{
    __shared__ float tile[64][65];   // [channel][pixel], +1 pad

    const int t   = blockIdx.x;
    const int kb  = blockIdx.y;
    const int px0 = t * 64;
    const size_t plane_in  = (size_t)kb * C_DIM * HW_DIM;
    const size_t plane_out = (size_t)kb * HW_DIM * C_DIM;
    const int tid = threadIdx.x;

    {
        const int pq = tid & 15;     // which float4 along the 64 pixels
        const int cg = tid >> 4;     // 0..15
#pragma unroll
        for (int r = 0; r < 4; ++r) {
            const int c = r * 16 + cg;
            const f4 v = __builtin_nontemporal_load(
                (const f4*)&img[plane_in + (size_t)c * HW_DIM + px0 + pq * 4]);
            tile[c][pq * 4 + 0] = v.x;
            tile[c][pq * 4 + 1] = v.y;
            tile[c][pq * 4 + 2] = v.z;
            tile[c][pq * 4 + 3] = v.w;
        }
    }
    __syncthreads();
    {
        const int c2 = (tid & 31) * 2;  // channel pair
        const int pg = tid >> 5;        // 0..7
#pragma unroll
        for (int r = 0; r < 8; ++r) {
            const int p = r * 8 + pg;
            const __half2 h = __floats2half2_rn(tile[c2][p], tile[c2 + 1][p]);
            *(__half2*)&wsp[plane_out + (size_t)(px0 + p) * C_DIM + c2] = h;
        }
    }
}

// ---------------------------------------------------------------------------
// Fuse, 2 voxels per thread for doubled memory-level parallelism:
// 16 lanes per voxel, each lane owns 4 channels (uint2 = 8B fp16 gather).
// All 12 camera gathers + both vox reads are independent and issued before
// any consumption. vox/out accesses stay fully coalesced per quarter-wave.
// ---------------------------------------------------------------------------
__global__ __launch_bounds__(256) void fuse_f16x2_kernel(
    const __half* __restrict__ wsp,  // (12, HW, 64) channel-last fp16
    const float*  __restrict__ vox,  // (N, 64)
    const int*    __restrict__ bidx, // (N,)
    const int*    __restrict__ gy,   // (6, N)
    const int*    __restrict__ gx,   // (6, N)
    const int*    __restrict__ mask, // (6, N)
    float*        __restrict__ out,  // (N, 64)
    int N, int half)
{
    const size_t gt = blockIdx.x * (size_t)blockDim.x + threadIdx.x;
    const int n0 = (int)(gt >> 4);
    const int q  = (int)(gt & 15);
    if (n0 >= half) return;
    const int n1 = n0 + half;
    const bool has1 = (n1 < N);
    const int n1c = has1 ? n1 : n0;          // clamped (loads safe, discarded)

    int m0[NUM_CAMS], y0[NUM_CAMS], x0[NUM_CAMS];
    int m1[NUM_CAMS], y1[NUM_CAMS], x1[NUM_CAMS];
#pragma unroll
    for (int k = 0; k < NUM_CAMS; ++k) {
        m0[k] = mask[(size_t)k * N + n0];
        y0[k] = gy[(size_t)k * N + n0];
        x0[k] = gx[(size_t)k * N + n0];
        m1[k] = mask[(size_t)k * N + n1c];
        y1[k] = gy[(size_t)k * N + n1c];
        x1[k] = gx[(size_t)k * N + n1c];
    }
    const int b0 = bidx[n0];
    const int b1 = bidx[n1c];

    f4 acc0 = __builtin_nontemporal_load((const f4*)vox + (size_t)n0 * 16 + q);
    f4 acc1 = __builtin_nontemporal_load((const f4*)vox + (size_t)n1c * 16 + q);

    const __half* base0 = wsp + (size_t)b0 * HW_DIM * C_DIM;
    const __half* base1 = wsp + (size_t)b1 * HW_DIM * C_DIM;

    uint2 rv0[NUM_CAMS], rv1[NUM_CAMS];
#pragma unroll
    for (int k = 0; k < NUM_CAMS; ++k) {
        rv0[k] = make_uint2(0u, 0u);
        rv1[k] = make_uint2(0u, 0u);
        if (m0[k] > 0) {
            const __half* p = base0
                + (size_t)k * ((size_t)B_DIM * HW_DIM * C_DIM)
                + ((size_t)y0[k] * W_DIM + x0[k]) * C_DIM;
            rv0[k] = *(const uint2*)(p + q * 4);
        }
        if (m1[k] > 0) {
            const __half* p = base1
                + (size_t)k * ((size_t)B_DIM * HW_DIM * C_DIM)
                + ((size_t)y1[k] * W_DIM + x1[k]) * C_DIM;
            rv1[k] = *(const uint2*)(p + q * 4);
        }
    }

#pragma unroll
    for (int k = 0; k < NUM_CAMS; ++k) {
        const float2 fa0 = __half22float2(*(const __half2*)&rv0[k].x);
        const float2 fc0 = __half22float2(*(const __half2*)&rv0[k].y);
        acc0.x += fa0.x; acc0.y += fa0.y; acc0.z += fc0.x; acc0.w += fc0.y;
        const float2 fa1 = __half22float2(*(const __half2*)&rv1[k].x);
        const float2 fc1 = __half22float2(*(const __half2*)&rv1[k].y);
        acc1.x += fa1.x; acc1.y += fa1.y; acc1.z += fc1.x; acc1.w += fc1.y;
    }

    __builtin_nontemporal_store(acc0, (f4*)out + (size_t)n0 * 16 + q);
    if (has1)
        __builtin_nontemporal_store(acc1, (f4*)out + (size_t)n1 * 16 + q);
}

// ---------------------------------------------------------------------------
// Fallback (round-1 kernel) if the workspace is too small for the fp16 copy.
// ---------------------------------------------------------------------------
__global__ __launch_bounds__(256) void fuse_direct_kernel(
    const float* __restrict__ img, const float* __restrict__ vox,
    const int* __restrict__ bidx, const int* __restrict__ gy,
    const int* __restrict__ gx, const int* __restrict__ mask,
    float* __restrict__ out, int N)
{
    const int wave = (int)((blockIdx.x * (size_t)blockDim.x + threadIdx.x) >> 6);
    const int c    = threadIdx.x & 63;
    if (wave >= N) return;
    const int n = wave;
    int m[NUM_CAMS], y[NUM_CAMS], x[NUM_CAMS];
#pragma unroll
    for (int k = 0; k < NUM_CAMS; ++k) {
        m[k] = mask[(size_t)k * N + n];
        y[k] = gy[(size_t)k * N + n];
        x[k] = gx[(size_t)k * N + n];
    }
    const int b = bidx[n];
    float acc = vox[(size_t)n * C_DIM + c];
    const float* base = img + ((size_t)b * C_DIM + c) * HW_DIM;
    float v[NUM_CAMS];
#pragma unroll
    for (int k = 0; k < NUM_CAMS; ++k) {
        v[k] = 0.0f;
        if (m[k] > 0)
            v[k] = base[(size_t)k * (B_DIM * C_DIM * (size_t)HW_DIM)
                        + (size_t)y[k] * W_DIM + (size_t)x[k]];
    }
    acc += ((v[0] + v[1]) + (v[2] + v[3])) + (v[4] + v[5]);
    out[(size_t)n * C_DIM + c] = acc;
}

extern "C" void kernel_launch(void* const* d_in, const int* in_sizes, int n_in,
                              void* d_out, int out_size, void* d_ws, size_t ws_size,
                              hipStream_t stream) {
    const float* img  = (const float*)d_in[0];
    const float* vox  = (const float*)d_in[1];
    const int*   bidx = (const int*)d_in[2];
    const int*   gy   = (const int*)d_in[3];
    const int*   gx   = (const int*)d_in[4];
    const int*   mask = (const int*)d_in[5];
    float* out = (float*)d_out;

    const int N = in_sizes[2];

    const size_t img_half_bytes = (size_t)PLANES * HW_DIM * C_DIM * sizeof(__half); // ~142 MB

    if (ws_size >= img_half_bytes) {
        __half* wsp = (__half*)d_ws;
        dim3 tgrid(TILES_PER_PLANE, PLANES);
        transpose_f16_kernel<<<tgrid, 256, 0, stream>>>(img, wsp);

        const int half = (N + 1) / 2;
        const size_t total_threads = (size_t)half * 16;
        const int blocks = (int)((total_threads + 255) / 256);
        fuse_f16x2_kernel<<<blocks, 256, 0, stream>>>(wsp, vox, bidx, gy, gx, mask, out, N, half);
    } else {
        const int blocks = (N * 64 + 255) / 256;
        fuse_direct_kernel<<<blocks, 256, 0, stream>>>(img, vox, bidx, gy, gx, mask, out, N);
    }
}

// Round 8
// 103.354 us; speedup vs baseline: 1.1408x; 1.0120x over previous
//
#include <hip/hip_runtime.h>
#include <hip/hip_fp16.h>

#define NUM_CAMS 6
#define B_DIM    2
#define C_DIM    64
#define H_DIM    232
#define W_DIM    400
#define HW_DIM   (H_DIM * W_DIM)          // 92800
#define TILES_PER_PLANE (HW_DIM / 64)     // 1450 (exact)
#define PLANES   (NUM_CAMS * B_DIM)       // 12
#define VPB      64                       // voxels per fuse block
#define ILP      4                        // voxels per thread

typedef float f4 __attribute__((ext_vector_type(4)));

// ---------------------------------------------------------------------------
// Transpose + downconvert: (k,b,c,h,w) fp32 -> (k,b,h,w,c) fp16.
// img read once -> non-temporal, preserving L3 residency for the fp16 copy.
// (unchanged from round 5/7 — clean A/B for the fuse change)
// ---------------------------------------------------------------------------
__global__ __launch_bounds__(256) void transpose_f16_kernel(
    const float* __restrict__ img,   // (12, 64, HW)
    __half*      __restrict__ wsp)   // (12, HW, 64)
{
    __shared__ float tile[64][65];   // [channel][pixel], +1 pad

    const int t   = blockIdx.x;
    const int kb  = blockIdx.y;
    const int px0 = t * 64;
    const size_t plane_in  = (size_t)kb * C_DIM * HW_DIM;
    const size_t plane_out = (size_t)kb * HW_DIM * C_DIM;
    const int tid = threadIdx.x;

    {
        const int pq = tid & 15;
        const int cg = tid >> 4;
#pragma unroll
        for (int r = 0; r < 4; ++r) {
            const int c = r * 16 + cg;
            const f4 v = __builtin_nontemporal_load(
                (const f4*)&img[plane_in + (size_t)c * HW_DIM + px0 + pq * 4]);
            tile[c][pq * 4 + 0] = v.x;
            tile[c][pq * 4 + 1] = v.y;
            tile[c][pq * 4 + 2] = v.z;
            tile[c][pq * 4 + 3] = v.w;
        }
    }
    __syncthreads();
    {
        const int c2 = (tid & 31) * 2;
        const int pg = tid >> 5;
#pragma unroll
        for (int r = 0; r < 8; ++r) {
            const int p = r * 8 + pg;
            const __half2 h = __floats2half2_rn(tile[c2][p], tile[c2 + 1][p]);
            *(__half2*)&wsp[plane_out + (size_t)(px0 + p) * C_DIM + c2] = h;
        }
    }
}

// ---------------------------------------------------------------------------
// Fuse: block = 64 voxels. Metadata staged cooperatively into LDS (coalesced,
// ~5 vector loads/thread) then broadcast-read; each thread owns 4 voxels x
// 4 channels and issues 24 independent 8B gathers before consuming any.
// ---------------------------------------------------------------------------
__global__ __launch_bounds__(256) void fuse_f16x4_kernel(
    const __half* __restrict__ wsp,  // (12, HW, 64) channel-last fp16
    const float*  __restrict__ vox,  // (N, 64)
    const int*    __restrict__ bidx, // (N,)
    const int*    __restrict__ gy,   // (6, N)
    const int*    __restrict__ gx,   // (6, N)
    const int*    __restrict__ mask, // (6, N)
    float*        __restrict__ out,  // (N, 64)
    int N)
{
    __shared__ int sm[NUM_CAMS][VPB];
    __shared__ int sy[NUM_CAMS][VPB];
    __shared__ int sx[NUM_CAMS][VPB];
    __shared__ int sb[VPB];

    const int v0  = blockIdx.x * VPB;
    const int tid = threadIdx.x;

    // Cooperative meta staging: 19 rows of 64 contiguous ints.
    // rows 0-5: mask[k], 6-11: gy[k], 12-17: gx[k], 18: bidx.
    {
        const int jj = tid & 63;
        const int v  = v0 + jj;
        const int vc = (v < N) ? v : (N - 1);
        for (int r = tid >> 6; r < 19; r += 4) {
            if (r < 6) {
                sm[r][jj] = (v < N) ? mask[(size_t)r * N + vc] : 0;
            } else if (r < 12) {
                sy[r - 6][jj] = gy[(size_t)(r - 6) * N + vc];
            } else if (r < 18) {
                sx[r - 12][jj] = gx[(size_t)(r - 12) * N + vc];
            } else {
                sb[jj] = bidx[vc];
            }
        }
    }
    __syncthreads();

    const int j = tid >> 4;      // voxel slot 0..15
    const int q = tid & 15;      // float4 index within channel vector

    f4 acc[ILP];
    uint2 rv[ILP][NUM_CAMS];
    int vn[ILP];

#pragma unroll
    for (int ii = 0; ii < ILP; ++ii) {
        const int s = j + ii * 16;
        const int v = v0 + s;
        vn[ii] = v;
        const int vc = (v < N) ? v : (N - 1);
        acc[ii] = __builtin_nontemporal_load((const f4*)vox + (size_t)vc * 16 + q);
    }

#pragma unroll
    for (int ii = 0; ii < ILP; ++ii) {
        const int s = j + ii * 16;
        const __half* base = wsp + (size_t)sb[s] * HW_DIM * C_DIM;
#pragma unroll
        for (int k = 0; k < NUM_CAMS; ++k) {
            rv[ii][k] = make_uint2(0u, 0u);
            if (sm[k][s] > 0) {
                const __half* p = base
                    + (size_t)k * ((size_t)B_DIM * HW_DIM * C_DIM)
                    + ((size_t)sy[k][s] * W_DIM + sx[k][s]) * C_DIM;
                rv[ii][k] = *(const uint2*)(p + q * 4);
            }
        }
    }

#pragma unroll
    for (int ii = 0; ii < ILP; ++ii) {
#pragma unroll
        for (int k = 0; k < NUM_CAMS; ++k) {
            const float2 fa = __half22float2(*(const __half2*)&rv[ii][k].x);
            const float2 fc = __half22float2(*(const __half2*)&rv[ii][k].y);
            acc[ii].x += fa.x; acc[ii].y += fa.y; acc[ii].z += fc.x; acc[ii].w += fc.y;
        }
        if (vn[ii] < N)
            __builtin_nontemporal_store(acc[ii], (f4*)out + (size_t)vn[ii] * 16 + q);
    }
}

// ---------------------------------------------------------------------------
// Fallback (round-1 kernel) if the workspace is too small for the fp16 copy.
// ---------------------------------------------------------------------------
__global__ __launch_bounds__(256) void fuse_direct_kernel(
    const float* __restrict__ img, const float* __restrict__ vox,
    const int* __restrict__ bidx, const int* __restrict__ gy,
    const int* __restrict__ gx, const int* __restrict__ mask,
    float* __restrict__ out, int N)
{
    const int wave = (int)((blockIdx.x * (size_t)blockDim.x + threadIdx.x) >> 6);
    const int c    = threadIdx.x & 63;
    if (wave >= N) return;
    const int n = wave;
    int m[NUM_CAMS], y[NUM_CAMS], x[NUM_CAMS];
#pragma unroll
    for (int k = 0; k < NUM_CAMS; ++k) {
        m[k] = mask[(size_t)k * N + n];
        y[k] = gy[(size_t)k * N + n];
        x[k] = gx[(size_t)k * N + n];
    }
    const int b = bidx[n];
    float acc = vox[(size_t)n * C_DIM + c];
    const float* base = img + ((size_t)b * C_DIM + c) * HW_DIM;
    float v[NUM_CAMS];
#pragma unroll
    for (int k = 0; k < NUM_CAMS; ++k) {
        v[k] = 0.0f;
        if (m[k] > 0)
            v[k] = base[(size_t)k * (B_DIM * C_DIM * (size_t)HW_DIM)
                        + (size_t)y[k] * W_DIM + (size_t)x[k]];
    }
    acc += ((v[0] + v[1]) + (v[2] + v[3])) + (v[4] + v[5]);
    out[(size_t)n * C_DIM + c] = acc;
}

extern "C" void kernel_launch(void* const* d_in, const int* in_sizes, int n_in,
                              void* d_out, int out_size, void* d_ws, size_t ws_size,
                              hipStream_t stream) {
    const float* img  = (const float*)d_in[0];
    const float* vox  = (const float*)d_in[1];
    const int*   bidx = (const int*)d_in[2];
    const int*   gy   = (const int*)d_in[3];
    const int*   gx   = (const int*)d_in[4];
    const int*   mask = (const int*)d_in[5];
    float* out = (float*)d_out;

    const int N = in_sizes[2];

    const size_t img_half_bytes = (size_t)PLANES * HW_DIM * C_DIM * sizeof(__half); // ~142 MB

    if (ws_size >= img_half_bytes) {
        __half* wsp = (__half*)d_ws;
        dim3 tgrid(TILES_PER_PLANE, PLANES);
        transpose_f16_kernel<<<tgrid, 256, 0, stream>>>(img, wsp);

        const int blocks = (N + VPB - 1) / VPB;
        fuse_f16x4_kernel<<<blocks, 256, 0, stream>>>(wsp, vox, bidx, gy, gx, mask, out, N);
    } else {
        const int blocks = (N * 64 + 255) / 256;
        fuse_direct_kernel<<<blocks, 256, 0, stream>>>(img, vox, bidx, gy, gx, mask, out, N);
    }
}